// Round 6
// baseline (2480.171 us; speedup 1.0000x reference)
//
#include <hip/hip_runtime.h>
#include <hip/hip_bf16.h>
#include <stdint.h>

// B=4, T=1024, C=1024, H=16, D=64, ks=16
// R14: single fused mega-kernel. Cross-round analysis showed a fixed ~148us
//      mass = inter-launch + harness overhead (kernels sum to ~90us). All 4
//      stages fused with device-scope grid barriers; grid 1024 x 256,
//      launch_bounds(256,4) + 30.5KB LDS union => 5 blocks/CU capacity,
//      co-residency guaranteed. Barrier: {cnt,gen} self-resetting, MAGIC-
//      checked init robust to zeroed/poisoned/persistent workspace.

typedef __bf16 bf16x8 __attribute__((ext_vector_type(8)));
typedef float f32x4 __attribute__((ext_vector_type(4)));

#define AS1(p) ((__attribute__((address_space(1))) void*)(p))
#define AS3(p) ((__attribute__((address_space(3))) void*)(p))

#define NBLK 1024u
#define MAGIC 0x5EEDF00Du

__device__ __forceinline__ void gridbar(unsigned int* bar, int idx) {
  __threadfence();            // release: my writes visible device-wide
  __syncthreads();            // all threads of block fenced
  if (threadIdx.x == 0) {
    unsigned int* cnt = bar + idx * 32;
    unsigned int* gen = cnt + 16;
    unsigned int g0 = __hip_atomic_load(gen, __ATOMIC_ACQUIRE, __HIP_MEMORY_SCOPE_AGENT);
    if (__hip_atomic_fetch_add(cnt, 1u, __ATOMIC_ACQ_REL, __HIP_MEMORY_SCOPE_AGENT)
        == NBLK - 1u) {
      __hip_atomic_store(cnt, 0u, __ATOMIC_RELAXED, __HIP_MEMORY_SCOPE_AGENT);
      __hip_atomic_fetch_add(gen, 1u, __ATOMIC_ACQ_REL, __HIP_MEMORY_SCOPE_AGENT);
    } else {
      while (__hip_atomic_load(gen, __ATOMIC_ACQUIRE, __HIP_MEMORY_SCOPE_AGENT) == g0)
        __builtin_amdgcn_s_sleep(2);
    }
  }
  __syncthreads();
  __threadfence();            // acquire: see other blocks' writes
}

// ------- bf16 NT GEMM tile: 128 rows x 64 cols, K=1024, BK=64 -------------
// LDS: As [2][128*32] @ smem (16KB), Bs [2][64*32] @ smem+16384 (8KB).
__device__ __forceinline__ void gemm128x64(
    const __hip_bfloat16* __restrict__ A, const __hip_bfloat16* __restrict__ Bw,
    __hip_bfloat16* __restrict__ C, char* smem)
{
  const int K = 1024, N = 1024;
  __hip_bfloat16* As = (__hip_bfloat16*)smem;           // [half][4096]
  __hip_bfloat16* Bs = (__hip_bfloat16*)(smem + 16384); // [half][2048]
  const int t = threadIdx.x;
  const int wv = t >> 6, lane = t & 63;
  const int wRow = (wv >> 1) * 64, wCol = (wv & 1) * 32;
  const int mrow = lane & 15, kq = lane >> 4;

  f32x4 acc[4][2] = {};

  for (int k0 = 0; k0 < K; k0 += 64) {
    __syncthreads();
#pragma unroll
    for (int tI = 0; tI < 6; ++tI) {
      int c = wv * 6 + tI;                    // 24 chunks of 1024B
      const __hip_bfloat16* gsrc;
      __hip_bfloat16* ldst;
      if (c < 16) {
        int half = c >> 3, ch = c & 7;
        int byteOff = ch * 1024 + lane * 16;
        gsrc = A + (size_t)(byteOff >> 6) * K + k0 + half * 32 + ((byteOff & 63) >> 1);
        ldst = As + half * 4096 + ch * 512;
      } else {
        int cb = c - 16; int half = cb >> 2, ch = cb & 3;
        int byteOff = ch * 1024 + lane * 16;
        gsrc = Bw + (size_t)(byteOff >> 6) * K + k0 + half * 32 + ((byteOff & 63) >> 1);
        ldst = Bs + half * 2048 + ch * 512;
      }
      __builtin_amdgcn_global_load_lds(AS1((void*)gsrc), AS3(ldst), 16, 0, 0);
    }
    __syncthreads();

#pragma unroll
    for (int half = 0; half < 2; ++half) {
      bf16x8 af[4], bf[2];
#pragma unroll
      for (int mi = 0; mi < 4; ++mi)
        af[mi] = *(const bf16x8*)&As[half * 4096 + (wRow + mi * 16 + mrow) * 32 + kq * 8];
#pragma unroll
      for (int ni = 0; ni < 2; ++ni)
        bf[ni] = *(const bf16x8*)&Bs[half * 2048 + (wCol + ni * 16 + mrow) * 32 + kq * 8];
#pragma unroll
      for (int mi = 0; mi < 4; ++mi)
#pragma unroll
        for (int ni = 0; ni < 2; ++ni)
          acc[mi][ni] = __builtin_amdgcn_mfma_f32_16x16x32_bf16(af[mi], bf[ni], acc[mi][ni], 0, 0, 0);
    }
  }

  // C/D layout: col = lane&15, row = (lane>>4)*4 + r   [m89-verified]
#pragma unroll
  for (int mi = 0; mi < 4; ++mi)
#pragma unroll
    for (int ni = 0; ni < 2; ++ni)
#pragma unroll
      for (int r = 0; r < 4; ++r) {
        int row = wRow + mi * 16 + kq * 4 + r;
        int col = wCol + ni * 16 + mrow;
        C[(size_t)row * N + col] = __float2bfloat16(acc[mi][ni][r]);
      }
}

__global__ __launch_bounds__(256, 4) void mega_kernel(
    const float* __restrict__ q, const float* __restrict__ k,
    const float* __restrict__ v, const float* __restrict__ Wq,
    const float* __restrict__ Wk, const float* __restrict__ Wv,
    const float* __restrict__ Wp, const float* __restrict__ bp,
    __hip_bfloat16* __restrict__ qkv_bf, __hip_bfloat16* __restrict__ w_bf,
    __hip_bfloat16* __restrict__ QKVp, __hip_bfloat16* __restrict__ OUTA,
    float* __restrict__ tails, float* __restrict__ vsump,
    unsigned int* __restrict__ bar, float* __restrict__ out)
{
  __shared__ __align__(16) char smem[30464];
  const int bi = blockIdx.x, t = threadIdx.x;

  // ---- barrier init (robust to zeroed / poisoned / persistent workspace) --
  unsigned int* rdy = bar + 256;
  if (bi == 0 && t == 0) {
    if (__hip_atomic_load(rdy, __ATOMIC_ACQUIRE, __HIP_MEMORY_SCOPE_AGENT) != MAGIC) {
      for (int i = 0; i < 4; ++i) {
        __hip_atomic_store(bar + i * 32, 0u, __ATOMIC_RELAXED, __HIP_MEMORY_SCOPE_AGENT);
        __hip_atomic_store(bar + i * 32 + 16, 0u, __ATOMIC_RELAXED, __HIP_MEMORY_SCOPE_AGENT);
      }
      __threadfence();
      __hip_atomic_store(rdy, MAGIC, __ATOMIC_RELEASE, __HIP_MEMORY_SCOPE_AGENT);
    }
  }

  // ================= P0: fp32->bf16 convert + vsum partials ================
  // units 0..16383: convert (256 float4 each); 16384..16619: vsum partial
  // vsump[rc][b][c] = sum of 16 fp32 v rows (tail rows j>=80).
  for (int u = bi; u < 16620; u += NBLK) {
    if (u < 16384) {
      int idx = u * 256 + t;
      const float* src; ushort4* dst; int i;
      if (idx < 3145728) {
        int which = idx >> 20; i = idx & 1048575;
        src = which == 0 ? q : which == 1 ? k : v;
        dst = (ushort4*)qkv_bf + (size_t)which * 1048576 + i;
      } else {
        int w = idx - 3145728; int which = w >> 18; i = w & 262143;
        src = which == 0 ? Wq : which == 1 ? Wk : which == 2 ? Wv : Wp;
        dst = (ushort4*)w_bf + w;
      }
      float4 val = ((const float4*)src)[i];
      union { ushort4 u4; __hip_bfloat16 h[4]; } c;
      c.h[0] = __float2bfloat16(val.x); c.h[1] = __float2bfloat16(val.y);
      c.h[2] = __float2bfloat16(val.z); c.h[3] = __float2bfloat16(val.w);
      dst[0] = c.u4;
    } else {
      int rcb = u - 16384;                     // 0..235
      int b = rcb / 59, rc = rcb % 59;
      int c0 = t * 4;
      int j0 = 80 + rc * 16;
      const float* base = v + ((size_t)(b * 1024 + j0)) * 1024 + c0;
      float s0 = 0.f, s1 = 0.f, s2 = 0.f, s3 = 0.f;
#pragma unroll
      for (int jj = 0; jj < 16; ++jj) {
        float4 tv = *(const float4*)(base + (size_t)jj * 1024);
        s0 += tv.x; s1 += tv.y; s2 += tv.z; s3 += tv.w;
      }
      float* dstp = vsump + ((size_t)rc * 4 + b) * 1024 + c0;
      dstp[0] = s0; dstp[1] = s1; dstp[2] = s2; dstp[3] = s3;
    }
  }

  // wait for barrier init, then grid barrier
  if (t == 0)
    while (__hip_atomic_load(rdy, __ATOMIC_ACQUIRE, __HIP_MEMORY_SCOPE_AGENT) != MAGIC)
      __builtin_amdgcn_s_sleep(2);
  __syncthreads();
  gridbar(bar, 0);

  // ================= P1: qkv GEMM (+ tails GEMV) ===========================
  // 1024 q/k units (1/block) + 64 v units (blocks 0..63) + 8 GEMV (64..71).
  {
    int g = bi;                                // q/k unit
    int z = g >> 9, r = g & 511, n = r >> 5, m = r & 31;
    gemm128x64(qkv_bf + (size_t)z * 4194304 + (size_t)m * 131072,
               w_bf + (size_t)z * 1048576 + (size_t)n * 65536,
               QKVp + (size_t)z * 4194304 + (size_t)m * 131072 + n * 64, smem);
  }
  if (bi < 64) {                               // v unit (reduced: 128 rows/b)
    int m = (bi >> 4) * 8, n = bi & 15;
    gemm128x64(qkv_bf + (size_t)2 * 4194304 + (size_t)m * 131072,
               w_bf + (size_t)2 * 1048576 + (size_t)n * 65536,
               QKVp + (size_t)2 * 4194304 + (size_t)m * 131072 + n * 64, smem);
  } else if (bi < 72) {                        // tails GEMV (reduce partials)
    const int lane = t & 63, wvv = t >> 6;
    int l = bi - 64;
    float vs[4][16];
#pragma unroll
    for (int b = 0; b < 4; ++b)
#pragma unroll
      for (int x = 0; x < 16; ++x) vs[b][x] = 0.f;
    for (int rc = 0; rc < 59; ++rc) {
#pragma unroll
      for (int b = 0; b < 4; ++b) {
        const float4* srcv = (const float4*)(vsump + ((size_t)rc * 4 + b) * 1024 + lane * 16);
#pragma unroll
        for (int i = 0; i < 4; ++i) {
          float4 tv = srcv[i];
          vs[b][i * 4 + 0] += tv.x; vs[b][i * 4 + 1] += tv.y;
          vs[b][i * 4 + 2] += tv.z; vs[b][i * 4 + 3] += tv.w;
        }
      }
    }
    const __hip_bfloat16* WvB = w_bf + (size_t)2 * 1048576;
    int c0 = l * 128 + wvv * 32;
    for (int r = 0; r < 32; ++r) {
      int c = c0 + r;
      const __hip_bfloat16* wrow = WvB + (size_t)c * 1024 + lane * 16;
      bf16x8 w0 = *(const bf16x8*)wrow;
      bf16x8 w1 = *(const bf16x8*)(wrow + 8);
      float p0 = 0.f, p1 = 0.f, p2 = 0.f, p3 = 0.f;
#pragma unroll
      for (int x = 0; x < 8; ++x) {
        float a = (float)w0[x], bq = (float)w1[x];
        p0 += a * vs[0][x] + bq * vs[0][8 + x];
        p1 += a * vs[1][x] + bq * vs[1][8 + x];
        p2 += a * vs[2][x] + bq * vs[2][8 + x];
        p3 += a * vs[3][x] + bq * vs[3][8 + x];
      }
#pragma unroll
      for (int off = 1; off < 64; off <<= 1) {
        p0 += __shfl_xor(p0, off, 64);
        p1 += __shfl_xor(p1, off, 64);
        p2 += __shfl_xor(p2, off, 64);
        p3 += __shfl_xor(p3, off, 64);
      }
      if (lane == 0) {
        tails[c] = p0; tails[1024 + c] = p1;
        tails[2048 + c] = p2; tails[3072 + c] = p3;
      }
    }
  }
  gridbar(bar, 1);

  // ================= P2: attention (per b,h,64-row i-tile) =================
  {
    const int u = bi;
    const int i0 = (u & 15) * 64, h = (u >> 4) & 15, b = u >> 8;
    const int lane = t & 63, wv = t >> 6;
    const __hip_bfloat16* QP = QKVp;
    const __hip_bfloat16* KP = QKVp + (size_t)4194304;
    const __hip_bfloat16* VP = QKVp + (size_t)2 * 4194304;

    float (*csl)[68] = (float(*)[68])smem;                       // 17408 B
    __hip_bfloat16 (*vpt)[104] = (__hip_bfloat16(*)[104])smem;   // overlay
    __hip_bfloat16 (*wlb)[96] = (__hip_bfloat16(*)[96])(smem + 17408); // 12288 B
    float* scl = (float*)(smem + 29696);
    float* tlw = (float*)(smem + 29952);
    float* tl  = (float*)(smem + 30208);

    if (t < 64) tl[t] = tails[(size_t)b * 1024 + h * 64 + t];

    // phase A: p = qp*kp/8, inclusive cumsum over d.
    {
      const int i = t >> 2, seg = t & 3;
      const size_t base = ((size_t)(b * 1024 + i0 + i)) * 1024 + h * 64 + seg * 16;
      bf16x8 q0 = *(const bf16x8*)(QP + base);
      bf16x8 q1 = *(const bf16x8*)(QP + base + 8);
      bf16x8 k0 = *(const bf16x8*)(KP + base);
      bf16x8 k1 = *(const bf16x8*)(KP + base + 8);
      float cs[16];
      float run = 0.0f;
#pragma unroll
      for (int x = 0; x < 8; ++x) {
        run += (float)q0[x] * (float)k0[x] * 0.125f;
        cs[x] = run;
      }
#pragma unroll
      for (int x = 0; x < 8; ++x) {
        run += (float)q1[x] * (float)k1[x] * 0.125f;
        cs[8 + x] = run;
      }
      float t1 = __shfl_up(run, 1, 4);
      float t2 = __shfl_up(run, 2, 4);
      float t3 = __shfl_up(run, 3, 4);
      float off = 0.0f;
      if (seg > 0) off += t1;
      if (seg > 1) off += t2;
      if (seg > 2) off += t3;
      float4* dst = (float4*)&csl[i][seg * 16];
#pragma unroll
      for (int x4 = 0; x4 < 4; ++x4)
        dst[x4] = make_float4(cs[4 * x4] + off, cs[4 * x4 + 1] + off,
                              cs[4 * x4 + 2] + off, cs[4 * x4 + 3] + off);
    }
    __syncthreads();

    // phase B: wei for j<80, softmax max/sum (tail logit = 0, count 944)
    {
      int i = t >> 2, jg = t & 3;
      float wloc[20];
      float mx = 0.0f;
#pragma unroll
      for (int qq = 0; qq < 20; ++qq) {
        int j = jg + 4 * qq;
        int s = j - 16; s = s < 0 ? 0 : s;
        int e = j + 16; e = e > 64 ? 64 : e;
        float w = csl[i][e - 1] - (s > 0 ? csl[i][s - 1] : 0.0f);
        wloc[qq] = w;
        mx = fmaxf(mx, w);
      }
      mx = fmaxf(mx, __shfl_xor(mx, 1, 64));
      mx = fmaxf(mx, __shfl_xor(mx, 2, 64));
      float sum = 0.0f;
#pragma unroll
      for (int qq = 0; qq < 20; ++qq) {
        float e_ = __expf(wloc[qq] - mx);
        wlb[i][jg + 4 * qq] = __float2bfloat16(e_);
        sum += e_;
      }
#pragma unroll
      for (int qq = 0; qq < 4; ++qq)
        wlb[i][80 + jg + 4 * qq] = __float2bfloat16(0.0f);
      sum += __shfl_xor(sum, 1, 64);
      sum += __shfl_xor(sum, 2, 64);
      float tw = __expf(-mx);
      sum += 944.0f * tw;
      if (jg == 0) { scl[i] = 1.0f / sum; tlw[i] = tw / sum; }
    }
    __syncthreads();   // all csl reads done -> safe to overlay with vpt

    // phase C: stage vp^T[d][j] for j<80; zero-pad j=80..95
    for (int idx = t; idx < 80 * 64; idx += 256) {
      int j = idx >> 6, d = idx & 63;
      vpt[d][j] = VP[((size_t)(b * 1024 + j)) * 1024 + h * 64 + d];
    }
    for (int idx = t; idx < 64 * 16; idx += 256) {
      int d = idx >> 4, j = 80 + (idx & 15);
      vpt[d][j] = __float2bfloat16(0.0f);
    }
    __syncthreads();

    // phase D: O[i][d] = sum_j wl[i][j] * vpt[d][j] (M=64,N=64,K=96)
    {
      const int mh = (wv >> 1) * 32, nh = (wv & 1) * 32;
      const int mrow = lane & 15, kq = lane >> 4;
      f32x4 acc[2][2] = {};
#pragma unroll
      for (int k0 = 0; k0 < 96; k0 += 32) {
        bf16x8 af[2], bf[2];
#pragma unroll
        for (int mi = 0; mi < 2; ++mi)
          af[mi] = *(const bf16x8*)&wlb[mh + mi * 16 + mrow][k0 + kq * 8];
#pragma unroll
        for (int ni = 0; ni < 2; ++ni)
          bf[ni] = *(const bf16x8*)&vpt[nh + ni * 16 + mrow][k0 + kq * 8];
#pragma unroll
        for (int mi = 0; mi < 2; ++mi)
#pragma unroll
          for (int ni = 0; ni < 2; ++ni)
            acc[mi][ni] = __builtin_amdgcn_mfma_f32_16x16x32_bf16(af[mi], bf[ni], acc[mi][ni], 0, 0, 0);
      }
#pragma unroll
      for (int mi = 0; mi < 2; ++mi)
#pragma unroll
        for (int ni = 0; ni < 2; ++ni)
#pragma unroll
          for (int r = 0; r < 4; ++r) {
            int i = mh + mi * 16 + kq * 4 + r;
            int d = nh + ni * 16 + mrow;
            float o = acc[mi][ni][r] * scl[i] + tlw[i] * tl[d];
            OUTA[((size_t)(b * 1024 + i0 + i)) * 1024 + h * 64 + d] = __float2bfloat16(o);
          }
    }
  }
  gridbar(bar, 2);

  // ================= P3: final GEMM (64x64 tiles, 1024 units) ==============
  {
    const int N = 1024, K = 1024;
    int m = bi & 63, n = bi >> 6;              // m fastest -> XCD A-strip reuse
    const __hip_bfloat16* A = OUTA + (size_t)m * 65536;
    const __hip_bfloat16* Bw = w_bf + (size_t)3 * 1048576 + (size_t)n * 65536;
    float* C = out + (size_t)m * 65536 + n * 64;
    const float* bias = bp + n * 64;

    __hip_bfloat16* As = (__hip_bfloat16*)smem;           // [2][2048]
    __hip_bfloat16* Bs = (__hip_bfloat16*)(smem + 8192);  // [2][2048]
    const int wv = t >> 6, lane = t & 63;
    const int wRow = (wv >> 1) * 32, wCol = (wv & 1) * 32;
    const int mrow = lane & 15, kq = lane >> 4;

    f32x4 acc[2][2] = {};

    for (int k0 = 0; k0 < K; k0 += 64) {
      __syncthreads();
#pragma unroll
      for (int tI = 0; tI < 4; ++tI) {
        int c = wv * 4 + tI;                   // 16 chunks of 1024B
        int half, ch;
        const __hip_bfloat16* gsrc;
        __hip_bfloat16* ldst;
        if (c < 8) { half = c >> 2; ch = c & 3;
          int byteOff = ch * 1024 + lane * 16;
          gsrc = A + (size_t)(byteOff >> 6) * K + k0 + half * 32 + ((byteOff & 63) >> 1);
          ldst = As + half * 2048 + ch * 512;
        } else { int cb = c - 8; half = cb >> 2; ch = cb & 3;
          int byteOff = ch * 1024 + lane * 16;
          gsrc = Bw + (size_t)(byteOff >> 6) * K + k0 + half * 32 + ((byteOff & 63) >> 1);
          ldst = Bs + half * 2048 + ch * 512;
        }
        __builtin_amdgcn_global_load_lds(AS1((void*)gsrc), AS3(ldst), 16, 0, 0);
      }
      __syncthreads();

#pragma unroll
      for (int half = 0; half < 2; ++half) {
        bf16x8 af[2], bf[2];
#pragma unroll
        for (int mi = 0; mi < 2; ++mi)
          af[mi] = *(const bf16x8*)&As[half * 2048 + (wRow + mi * 16 + mrow) * 32 + kq * 8];
#pragma unroll
        for (int ni = 0; ni < 2; ++ni)
          bf[ni] = *(const bf16x8*)&Bs[half * 2048 + (wCol + ni * 16 + mrow) * 32 + kq * 8];
#pragma unroll
        for (int mi = 0; mi < 2; ++mi)
#pragma unroll
          for (int ni = 0; ni < 2; ++ni)
            acc[mi][ni] = __builtin_amdgcn_mfma_f32_16x16x32_bf16(af[mi], bf[ni], acc[mi][ni], 0, 0, 0);
      }
    }

#pragma unroll
    for (int mi = 0; mi < 2; ++mi)
#pragma unroll
      for (int ni = 0; ni < 2; ++ni)
#pragma unroll
        for (int r = 0; r < 4; ++r) {
          int row = wRow + mi * 16 + kq * 4 + r;
          int col = wCol + ni * 16 + mrow;
          __builtin_nontemporal_store(acc[mi][ni][r] + bias[col],
                                      &C[(size_t)row * N + col]);
        }
  }
}

// ---------------- launch ---------------------------------------------------
extern "C" void kernel_launch(void* const* d_in, const int* in_sizes, int n_in,
                              void* d_out, int out_size, void* d_ws, size_t ws_size,
                              hipStream_t stream)
{
  (void)in_sizes; (void)n_in; (void)out_size; (void)ws_size;
  const float* q  = (const float*)d_in[0];
  const float* k  = (const float*)d_in[1];
  const float* v  = (const float*)d_in[2];
  const float* Wq = (const float*)d_in[3];
  const float* Wk = (const float*)d_in[4];
  const float* Wv = (const float*)d_in[5];
  const float* Wp = (const float*)d_in[6];
  const float* bp = (const float*)d_in[7];

  char* ws = (char*)d_ws;
  __hip_bfloat16* qkv_bf = (__hip_bfloat16*)(ws);              // 24 MB
  __hip_bfloat16* w_bf   = (__hip_bfloat16*)(ws + 25165824);   // 8 MB
  __hip_bfloat16* QKVp   = (__hip_bfloat16*)(ws + 33554432);   // 24 MB
  __hip_bfloat16* OUTA   = (__hip_bfloat16*)(ws + 58720256);   // 8 MB
  float*          tails  = (float*)(ws + 67108864);            // 16 KB
  float*          vsump  = (float*)(ws + 67108864 + 16384);    // 944 KB partials
  unsigned int*   bar    = (unsigned int*)(ws + 68157440);     // barrier state
  float* out = (float*)d_out;

  mega_kernel<<<dim3(NBLK), 256, 0, stream>>>(
      q, k, v, Wq, Wk, Wv, Wp, bp,
      qkv_bf, w_bf, QKVp, OUTA, tails, vsump, bar, out);
}

// Round 7
// 614.523 us; speedup vs baseline: 4.0359x; 4.0359x over previous
//
#include <hip/hip_runtime.h>
#include <hip/hip_bf16.h>
#include <stdint.h>

// B=4, T=1024, C=1024, H=16, D=64, ks=16
// R15: fused mega-kernel, barrier protocol fixed. R14's 2.4ms came from
//      (a) per-thread __threadfence (1.5M agent fences -> L2 wb/inv) and
//      (b) ACQUIRE polling: every spin iteration emits buffer_inv (L1+L2
//      invalidate, required on non-coherent multi-XCD) -> ~950 idle blocks
//      nuked L2 every ~150ns -> 100 GB/s HBM crawl (counters: occ 49% = all
//      resident, VALU 0.75%). Fix: RELAXED polls (sc1 reads at coherence
//      point, no inv) + ONE release fence before arrive + ONE acquire fence
//      after release, thread 0 only.

typedef __bf16 bf16x8 __attribute__((ext_vector_type(8)));
typedef float f32x4 __attribute__((ext_vector_type(4)));

#define AS1(p) ((__attribute__((address_space(1))) void*)(p))
#define AS3(p) ((__attribute__((address_space(3))) void*)(p))

#define NBLK 1024u
#define MAGIC 0x5EEDF00Du

// Grid barrier: arrive via relaxed RMW (atomics carry sc1 -> coherence point),
// depart via relaxed poll + single acquire fence. Release fence before the
// RMW flushes this XCD's L2 once per block (syncthreads already drained
// vmcnt, so all waves' stores are in L2 by then).
__device__ __forceinline__ void gridbar(unsigned int* bar, int idx) {
  __syncthreads();                     // all waves' stores drained to L2
  if (threadIdx.x == 0) {
    unsigned int* cnt = bar + idx * 32;
    unsigned int* gen = cnt + 16;
    unsigned int g0 = __hip_atomic_load(gen, __ATOMIC_RELAXED, __HIP_MEMORY_SCOPE_AGENT);
    __builtin_amdgcn_fence(__ATOMIC_RELEASE, "agent");   // L2 writeback, once
    if (__hip_atomic_fetch_add(cnt, 1u, __ATOMIC_RELAXED, __HIP_MEMORY_SCOPE_AGENT)
        == NBLK - 1u) {
      __hip_atomic_store(cnt, 0u, __ATOMIC_RELAXED, __HIP_MEMORY_SCOPE_AGENT);
      __hip_atomic_store(gen, g0 + 1u, __ATOMIC_RELAXED, __HIP_MEMORY_SCOPE_AGENT);
    } else {
      while (__hip_atomic_load(gen, __ATOMIC_RELAXED, __HIP_MEMORY_SCOPE_AGENT) == g0)
        __builtin_amdgcn_s_sleep(16);                    // ~1024 cyc/poll
    }
    __builtin_amdgcn_fence(__ATOMIC_ACQUIRE, "agent");   // L1/L2 inv, once
  }
  __syncthreads();                     // other waves held until fence done
}

// ------- bf16 NT GEMM tile: 128 rows x 64 cols, K=1024, BK=64 -------------
// LDS: As [2][128*32] @ smem (16KB), Bs [2][64*32] @ smem+16384 (8KB).
__device__ __forceinline__ void gemm128x64(
    const __hip_bfloat16* __restrict__ A, const __hip_bfloat16* __restrict__ Bw,
    __hip_bfloat16* __restrict__ C, char* smem)
{
  const int K = 1024, N = 1024;
  __hip_bfloat16* As = (__hip_bfloat16*)smem;           // [half][4096]
  __hip_bfloat16* Bs = (__hip_bfloat16*)(smem + 16384); // [half][2048]
  const int t = threadIdx.x;
  const int wv = t >> 6, lane = t & 63;
  const int wRow = (wv >> 1) * 64, wCol = (wv & 1) * 32;
  const int mrow = lane & 15, kq = lane >> 4;

  f32x4 acc[4][2] = {};

  for (int k0 = 0; k0 < K; k0 += 64) {
    __syncthreads();
#pragma unroll
    for (int tI = 0; tI < 6; ++tI) {
      int c = wv * 6 + tI;                    // 24 chunks of 1024B
      const __hip_bfloat16* gsrc;
      __hip_bfloat16* ldst;
      if (c < 16) {
        int half = c >> 3, ch = c & 7;
        int byteOff = ch * 1024 + lane * 16;
        gsrc = A + (size_t)(byteOff >> 6) * K + k0 + half * 32 + ((byteOff & 63) >> 1);
        ldst = As + half * 4096 + ch * 512;
      } else {
        int cb = c - 16; int half = cb >> 2, ch = cb & 3;
        int byteOff = ch * 1024 + lane * 16;
        gsrc = Bw + (size_t)(byteOff >> 6) * K + k0 + half * 32 + ((byteOff & 63) >> 1);
        ldst = Bs + half * 2048 + ch * 512;
      }
      __builtin_amdgcn_global_load_lds(AS1((void*)gsrc), AS3(ldst), 16, 0, 0);
    }
    __syncthreads();

#pragma unroll
    for (int half = 0; half < 2; ++half) {
      bf16x8 af[4], bf[2];
#pragma unroll
      for (int mi = 0; mi < 4; ++mi)
        af[mi] = *(const bf16x8*)&As[half * 4096 + (wRow + mi * 16 + mrow) * 32 + kq * 8];
#pragma unroll
      for (int ni = 0; ni < 2; ++ni)
        bf[ni] = *(const bf16x8*)&Bs[half * 2048 + (wCol + ni * 16 + mrow) * 32 + kq * 8];
#pragma unroll
      for (int mi = 0; mi < 4; ++mi)
#pragma unroll
        for (int ni = 0; ni < 2; ++ni)
          acc[mi][ni] = __builtin_amdgcn_mfma_f32_16x16x32_bf16(af[mi], bf[ni], acc[mi][ni], 0, 0, 0);
    }
  }

  // C/D layout: col = lane&15, row = (lane>>4)*4 + r   [m89-verified]
#pragma unroll
  for (int mi = 0; mi < 4; ++mi)
#pragma unroll
    for (int ni = 0; ni < 2; ++ni)
#pragma unroll
      for (int r = 0; r < 4; ++r) {
        int row = wRow + mi * 16 + kq * 4 + r;
        int col = wCol + ni * 16 + mrow;
        C[(size_t)row * N + col] = __float2bfloat16(acc[mi][ni][r]);
      }
}

__global__ __launch_bounds__(256, 4) void mega_kernel(
    const float* __restrict__ q, const float* __restrict__ k,
    const float* __restrict__ v, const float* __restrict__ Wq,
    const float* __restrict__ Wk, const float* __restrict__ Wv,
    const float* __restrict__ Wp, const float* __restrict__ bp,
    __hip_bfloat16* __restrict__ qkv_bf, __hip_bfloat16* __restrict__ w_bf,
    __hip_bfloat16* __restrict__ QKVp, __hip_bfloat16* __restrict__ OUTA,
    float* __restrict__ tails, float* __restrict__ vsump,
    unsigned int* __restrict__ bar, float* __restrict__ out)
{
  __shared__ __align__(16) char smem[30464];
  const int bi = blockIdx.x, t = threadIdx.x;

  // ---- barrier init (robust to zeroed / poisoned / persistent workspace) --
  unsigned int* rdy = bar + 256;
  if (bi == 0 && t == 0) {
    if (__hip_atomic_load(rdy, __ATOMIC_RELAXED, __HIP_MEMORY_SCOPE_AGENT) != MAGIC) {
      for (int i = 0; i < 4; ++i) {
        __hip_atomic_store(bar + i * 32, 0u, __ATOMIC_RELAXED, __HIP_MEMORY_SCOPE_AGENT);
        __hip_atomic_store(bar + i * 32 + 16, 0u, __ATOMIC_RELAXED, __HIP_MEMORY_SCOPE_AGENT);
      }
      __builtin_amdgcn_fence(__ATOMIC_RELEASE, "agent");
      __hip_atomic_store(rdy, MAGIC, __ATOMIC_RELAXED, __HIP_MEMORY_SCOPE_AGENT);
    }
  }

  // ================= P0: fp32->bf16 convert + vsum partials ================
  // units 0..16383: convert (256 float4 each); 16384..16619: vsum partial
  // vsump[rc][b][c] = sum of 16 fp32 v rows (tail rows j>=80).
  for (int u = bi; u < 16620; u += NBLK) {
    if (u < 16384) {
      int idx = u * 256 + t;
      const float* src; ushort4* dst; int i;
      if (idx < 3145728) {
        int which = idx >> 20; i = idx & 1048575;
        src = which == 0 ? q : which == 1 ? k : v;
        dst = (ushort4*)qkv_bf + (size_t)which * 1048576 + i;
      } else {
        int w = idx - 3145728; int which = w >> 18; i = w & 262143;
        src = which == 0 ? Wq : which == 1 ? Wk : which == 2 ? Wv : Wp;
        dst = (ushort4*)w_bf + w;
      }
      float4 val = ((const float4*)src)[i];
      union { ushort4 u4; __hip_bfloat16 h[4]; } c;
      c.h[0] = __float2bfloat16(val.x); c.h[1] = __float2bfloat16(val.y);
      c.h[2] = __float2bfloat16(val.z); c.h[3] = __float2bfloat16(val.w);
      dst[0] = c.u4;
    } else {
      int rcb = u - 16384;                     // 0..235
      int b = rcb / 59, rc = rcb % 59;
      int c0 = t * 4;
      int j0 = 80 + rc * 16;
      const float* base = v + ((size_t)(b * 1024 + j0)) * 1024 + c0;
      float s0 = 0.f, s1 = 0.f, s2 = 0.f, s3 = 0.f;
#pragma unroll
      for (int jj = 0; jj < 16; ++jj) {
        float4 tv = *(const float4*)(base + (size_t)jj * 1024);
        s0 += tv.x; s1 += tv.y; s2 += tv.z; s3 += tv.w;
      }
      float* dstp = vsump + ((size_t)rc * 4 + b) * 1024 + c0;
      dstp[0] = s0; dstp[1] = s1; dstp[2] = s2; dstp[3] = s3;
    }
  }

  // wait for barrier init (relaxed poll; acquire folded into gridbar)
  if (t == 0)
    while (__hip_atomic_load(rdy, __ATOMIC_RELAXED, __HIP_MEMORY_SCOPE_AGENT) != MAGIC)
      __builtin_amdgcn_s_sleep(16);
  gridbar(bar, 0);

  // ================= P1: qkv GEMM (+ tails GEMV) ===========================
  // 1024 q/k units (1/block) + 64 v units (blocks 0..63) + 8 GEMV (64..71).
  {
    int g = bi;                                // q/k unit
    int z = g >> 9, r = g & 511, n = r >> 5, m = r & 31;
    gemm128x64(qkv_bf + (size_t)z * 4194304 + (size_t)m * 131072,
               w_bf + (size_t)z * 1048576 + (size_t)n * 65536,
               QKVp + (size_t)z * 4194304 + (size_t)m * 131072 + n * 64, smem);
  }
  if (bi < 64) {                               // v unit (reduced: 128 rows/b)
    int m = (bi >> 4) * 8, n = bi & 15;
    gemm128x64(qkv_bf + (size_t)2 * 4194304 + (size_t)m * 131072,
               w_bf + (size_t)2 * 1048576 + (size_t)n * 65536,
               QKVp + (size_t)2 * 4194304 + (size_t)m * 131072 + n * 64, smem);
  } else if (bi < 72) {                        // tails GEMV (reduce partials)
    const int lane = t & 63, wvv = t >> 6;
    int l = bi - 64;
    float vs[4][16];
#pragma unroll
    for (int b = 0; b < 4; ++b)
#pragma unroll
      for (int x = 0; x < 16; ++x) vs[b][x] = 0.f;
    for (int rc = 0; rc < 59; ++rc) {
#pragma unroll
      for (int b = 0; b < 4; ++b) {
        const float4* srcv = (const float4*)(vsump + ((size_t)rc * 4 + b) * 1024 + lane * 16);
#pragma unroll
        for (int i = 0; i < 4; ++i) {
          float4 tv = srcv[i];
          vs[b][i * 4 + 0] += tv.x; vs[b][i * 4 + 1] += tv.y;
          vs[b][i * 4 + 2] += tv.z; vs[b][i * 4 + 3] += tv.w;
        }
      }
    }
    const __hip_bfloat16* WvB = w_bf + (size_t)2 * 1048576;
    int c0 = l * 128 + wvv * 32;
    for (int r = 0; r < 32; ++r) {
      int c = c0 + r;
      const __hip_bfloat16* wrow = WvB + (size_t)c * 1024 + lane * 16;
      bf16x8 w0 = *(const bf16x8*)wrow;
      bf16x8 w1 = *(const bf16x8*)(wrow + 8);
      float p0 = 0.f, p1 = 0.f, p2 = 0.f, p3 = 0.f;
#pragma unroll
      for (int x = 0; x < 8; ++x) {
        float a = (float)w0[x], bq = (float)w1[x];
        p0 += a * vs[0][x] + bq * vs[0][8 + x];
        p1 += a * vs[1][x] + bq * vs[1][8 + x];
        p2 += a * vs[2][x] + bq * vs[2][8 + x];
        p3 += a * vs[3][x] + bq * vs[3][8 + x];
      }
#pragma unroll
      for (int off = 1; off < 64; off <<= 1) {
        p0 += __shfl_xor(p0, off, 64);
        p1 += __shfl_xor(p1, off, 64);
        p2 += __shfl_xor(p2, off, 64);
        p3 += __shfl_xor(p3, off, 64);
      }
      if (lane == 0) {
        tails[c] = p0; tails[1024 + c] = p1;
        tails[2048 + c] = p2; tails[3072 + c] = p3;
      }
    }
  }
  gridbar(bar, 1);

  // ================= P2: attention (per b,h,64-row i-tile) =================
  {
    const int u = bi;
    const int i0 = (u & 15) * 64, h = (u >> 4) & 15, b = u >> 8;
    const int lane = t & 63, wv = t >> 6;
    const __hip_bfloat16* QP = QKVp;
    const __hip_bfloat16* KP = QKVp + (size_t)4194304;
    const __hip_bfloat16* VP = QKVp + (size_t)2 * 4194304;

    float (*csl)[68] = (float(*)[68])smem;                       // 17408 B
    __hip_bfloat16 (*vpt)[104] = (__hip_bfloat16(*)[104])smem;   // overlay
    __hip_bfloat16 (*wlb)[96] = (__hip_bfloat16(*)[96])(smem + 17408); // 12288 B
    float* scl = (float*)(smem + 29696);
    float* tlw = (float*)(smem + 29952);
    float* tl  = (float*)(smem + 30208);

    if (t < 64) tl[t] = tails[(size_t)b * 1024 + h * 64 + t];

    // phase A: p = qp*kp/8, inclusive cumsum over d.
    {
      const int i = t >> 2, seg = t & 3;
      const size_t base = ((size_t)(b * 1024 + i0 + i)) * 1024 + h * 64 + seg * 16;
      bf16x8 q0 = *(const bf16x8*)(QP + base);
      bf16x8 q1 = *(const bf16x8*)(QP + base + 8);
      bf16x8 k0 = *(const bf16x8*)(KP + base);
      bf16x8 k1 = *(const bf16x8*)(KP + base + 8);
      float cs[16];
      float run = 0.0f;
#pragma unroll
      for (int x = 0; x < 8; ++x) {
        run += (float)q0[x] * (float)k0[x] * 0.125f;
        cs[x] = run;
      }
#pragma unroll
      for (int x = 0; x < 8; ++x) {
        run += (float)q1[x] * (float)k1[x] * 0.125f;
        cs[8 + x] = run;
      }
      float t1 = __shfl_up(run, 1, 4);
      float t2 = __shfl_up(run, 2, 4);
      float t3 = __shfl_up(run, 3, 4);
      float off = 0.0f;
      if (seg > 0) off += t1;
      if (seg > 1) off += t2;
      if (seg > 2) off += t3;
      float4* dst = (float4*)&csl[i][seg * 16];
#pragma unroll
      for (int x4 = 0; x4 < 4; ++x4)
        dst[x4] = make_float4(cs[4 * x4] + off, cs[4 * x4 + 1] + off,
                              cs[4 * x4 + 2] + off, cs[4 * x4 + 3] + off);
    }
    __syncthreads();

    // phase B: wei for j<80, softmax max/sum (tail logit = 0, count 944)
    {
      int i = t >> 2, jg = t & 3;
      float wloc[20];
      float mx = 0.0f;
#pragma unroll
      for (int qq = 0; qq < 20; ++qq) {
        int j = jg + 4 * qq;
        int s = j - 16; s = s < 0 ? 0 : s;
        int e = j + 16; e = e > 64 ? 64 : e;
        float w = csl[i][e - 1] - (s > 0 ? csl[i][s - 1] : 0.0f);
        wloc[qq] = w;
        mx = fmaxf(mx, w);
      }
      mx = fmaxf(mx, __shfl_xor(mx, 1, 64));
      mx = fmaxf(mx, __shfl_xor(mx, 2, 64));
      float sum = 0.0f;
#pragma unroll
      for (int qq = 0; qq < 20; ++qq) {
        float e_ = __expf(wloc[qq] - mx);
        wlb[i][jg + 4 * qq] = __float2bfloat16(e_);
        sum += e_;
      }
#pragma unroll
      for (int qq = 0; qq < 4; ++qq)
        wlb[i][80 + jg + 4 * qq] = __float2bfloat16(0.0f);
      sum += __shfl_xor(sum, 1, 64);
      sum += __shfl_xor(sum, 2, 64);
      float tw = __expf(-mx);
      sum += 944.0f * tw;
      if (jg == 0) { scl[i] = 1.0f / sum; tlw[i] = tw / sum; }
    }
    __syncthreads();   // all csl reads done -> safe to overlay with vpt

    // phase C: stage vp^T[d][j] for j<80; zero-pad j=80..95
    for (int idx = t; idx < 80 * 64; idx += 256) {
      int j = idx >> 6, d = idx & 63;
      vpt[d][j] = VP[((size_t)(b * 1024 + j)) * 1024 + h * 64 + d];
    }
    for (int idx = t; idx < 64 * 16; idx += 256) {
      int d = idx >> 4, j = 80 + (idx & 15);
      vpt[d][j] = __float2bfloat16(0.0f);
    }
    __syncthreads();

    // phase D: O[i][d] = sum_j wl[i][j] * vpt[d][j] (M=64,N=64,K=96)
    {
      const int mh = (wv >> 1) * 32, nh = (wv & 1) * 32;
      const int mrow = lane & 15, kq = lane >> 4;
      f32x4 acc[2][2] = {};
#pragma unroll
      for (int k0 = 0; k0 < 96; k0 += 32) {
        bf16x8 af[2], bf[2];
#pragma unroll
        for (int mi = 0; mi < 2; ++mi)
          af[mi] = *(const bf16x8*)&wlb[mh + mi * 16 + mrow][k0 + kq * 8];
#pragma unroll
        for (int ni = 0; ni < 2; ++ni)
          bf[ni] = *(const bf16x8*)&vpt[nh + ni * 16 + mrow][k0 + kq * 8];
#pragma unroll
        for (int mi = 0; mi < 2; ++mi)
#pragma unroll
          for (int ni = 0; ni < 2; ++ni)
            acc[mi][ni] = __builtin_amdgcn_mfma_f32_16x16x32_bf16(af[mi], bf[ni], acc[mi][ni], 0, 0, 0);
      }
#pragma unroll
      for (int mi = 0; mi < 2; ++mi)
#pragma unroll
        for (int ni = 0; ni < 2; ++ni)
#pragma unroll
          for (int r = 0; r < 4; ++r) {
            int i = mh + mi * 16 + kq * 4 + r;
            int d = nh + ni * 16 + mrow;
            float o = acc[mi][ni][r] * scl[i] + tlw[i] * tl[d];
            OUTA[((size_t)(b * 1024 + i0 + i)) * 1024 + h * 64 + d] = __float2bfloat16(o);
          }
    }
  }
  gridbar(bar, 2);

  // ================= P3: final GEMM (64x64 tiles, 1024 units) ==============
  {
    const int N = 1024, K = 1024;
    int m = bi & 63, n = bi >> 6;              // m fastest -> XCD A-strip reuse
    const __hip_bfloat16* A = OUTA + (size_t)m * 65536;
    const __hip_bfloat16* Bw = w_bf + (size_t)3 * 1048576 + (size_t)n * 65536;
    float* C = out + (size_t)m * 65536 + n * 64;
    const float* bias = bp + n * 64;

    __hip_bfloat16* As = (__hip_bfloat16*)smem;           // [2][2048]
    __hip_bfloat16* Bs = (__hip_bfloat16*)(smem + 8192);  // [2][2048]
    const int wv = t >> 6, lane = t & 63;
    const int wRow = (wv >> 1) * 32, wCol = (wv & 1) * 32;
    const int mrow = lane & 15, kq = lane >> 4;

    f32x4 acc[2][2] = {};

    for (int k0 = 0; k0 < K; k0 += 64) {
      __syncthreads();
#pragma unroll
      for (int tI = 0; tI < 4; ++tI) {
        int c = wv * 4 + tI;                   // 16 chunks of 1024B
        int half, ch;
        const __hip_bfloat16* gsrc;
        __hip_bfloat16* ldst;
        if (c < 8) { half = c >> 2; ch = c & 3;
          int byteOff = ch * 1024 + lane * 16;
          gsrc = A + (size_t)(byteOff >> 6) * K + k0 + half * 32 + ((byteOff & 63) >> 1);
          ldst = As + half * 2048 + ch * 512;
        } else { int cb = c - 8; half = cb >> 2; ch = cb & 3;
          int byteOff = ch * 1024 + lane * 16;
          gsrc = Bw + (size_t)(byteOff >> 6) * K + k0 + half * 32 + ((byteOff & 63) >> 1);
          ldst = Bs + half * 2048 + ch * 512;
        }
        __builtin_amdgcn_global_load_lds(AS1((void*)gsrc), AS3(ldst), 16, 0, 0);
      }
      __syncthreads();

#pragma unroll
      for (int half = 0; half < 2; ++half) {
        bf16x8 af[2], bf[2];
#pragma unroll
        for (int mi = 0; mi < 2; ++mi)
          af[mi] = *(const bf16x8*)&As[half * 2048 + (wRow + mi * 16 + mrow) * 32 + kq * 8];
#pragma unroll
        for (int ni = 0; ni < 2; ++ni)
          bf[ni] = *(const bf16x8*)&Bs[half * 2048 + (wCol + ni * 16 + mrow) * 32 + kq * 8];
#pragma unroll
        for (int mi = 0; mi < 2; ++mi)
#pragma unroll
          for (int ni = 0; ni < 2; ++ni)
            acc[mi][ni] = __builtin_amdgcn_mfma_f32_16x16x32_bf16(af[mi], bf[ni], acc[mi][ni], 0, 0, 0);
      }
    }

#pragma unroll
    for (int mi = 0; mi < 2; ++mi)
#pragma unroll
      for (int ni = 0; ni < 2; ++ni)
#pragma unroll
        for (int r = 0; r < 4; ++r) {
          int row = wRow + mi * 16 + kq * 4 + r;
          int col = wCol + ni * 16 + mrow;
          __builtin_nontemporal_store(acc[mi][ni][r] + bias[col],
                                      &C[(size_t)row * N + col]);
        }
  }
}

// ---------------- launch ---------------------------------------------------
extern "C" void kernel_launch(void* const* d_in, const int* in_sizes, int n_in,
                              void* d_out, int out_size, void* d_ws, size_t ws_size,
                              hipStream_t stream)
{
  (void)in_sizes; (void)n_in; (void)out_size; (void)ws_size;
  const float* q  = (const float*)d_in[0];
  const float* k  = (const float*)d_in[1];
  const float* v  = (const float*)d_in[2];
  const float* Wq = (const float*)d_in[3];
  const float* Wk = (const float*)d_in[4];
  const float* Wv = (const float*)d_in[5];
  const float* Wp = (const float*)d_in[6];
  const float* bp = (const float*)d_in[7];

  char* ws = (char*)d_ws;
  __hip_bfloat16* qkv_bf = (__hip_bfloat16*)(ws);              // 24 MB
  __hip_bfloat16* w_bf   = (__hip_bfloat16*)(ws + 25165824);   // 8 MB
  __hip_bfloat16* QKVp   = (__hip_bfloat16*)(ws + 33554432);   // 24 MB
  __hip_bfloat16* OUTA   = (__hip_bfloat16*)(ws + 58720256);   // 8 MB
  float*          tails  = (float*)(ws + 67108864);            // 16 KB
  float*          vsump  = (float*)(ws + 67108864 + 16384);    // 944 KB partials
  unsigned int*   bar    = (unsigned int*)(ws + 68157440);     // barrier state
  float* out = (float*)d_out;

  mega_kernel<<<dim3(NBLK), 256, 0, stream>>>(
      q, k, v, Wq, Wk, Wv, Wp, bp,
      qkv_bf, w_bf, QKVp, OUTA, tails, vsump, bar, out);
}

// Round 8
// 178.061 us; speedup vs baseline: 13.9287x; 3.4512x over previous
//
#include <hip/hip_runtime.h>
#include <hip/hip_bf16.h>
#include <stdint.h>

// B=4, T=1024, C=1024, H=16, D=64, ks=16
// wei[b,h,i,j] = cs[i][e(j)] - cs[i][s(j)], s=clip(j-16,0,64), e=clip(j+16,0,64)
// => wei==0 for j>=80; softmax tail folds into one weight * tail-sum of vp.
// R16: full revert to the R8 anchor (175-181us proven). Session evidence:
//      reduced-V + side-kernels (R9-R13) all neutral-to-worse vs tail atomics
//      fused in the V-epilogue; mega-kernel grid-barrier path (R14/R15) is
//      4.5x off even after the fence fix -- abandoned per decision rule.

typedef __bf16 bf16x8 __attribute__((ext_vector_type(8)));
typedef float f32x4 __attribute__((ext_vector_type(4)));

#define AS1(p) ((__attribute__((address_space(1))) void*)(p))
#define AS3(p) ((__attribute__((address_space(3))) void*)(p))

// ---------------- fused fp32 -> bf16 convert (float4 per thread) ----------
// flat: idx<3M -> q,k,v (1M float4 each); else -> Wq,Wk,Wv,Wp (256K each).
// Block 16384 zeroes the 4096-float tails buffer (replaces hipMemsetAsync;
// safe: qkv (consumer) is a later launch on the same stream).
__global__ __launch_bounds__(256) void cvt_kernel(
    const float* __restrict__ q, const float* __restrict__ k,
    const float* __restrict__ v, const float* __restrict__ Wq,
    const float* __restrict__ Wk, const float* __restrict__ Wv,
    const float* __restrict__ Wp,
    ushort4* __restrict__ qkv_bf, ushort4* __restrict__ w_bf,
    float* __restrict__ tails)
{
  if (blockIdx.x == 16384) {
    float4* tz = (float4*)tails;
    tz[threadIdx.x * 4 + 0] = make_float4(0.f, 0.f, 0.f, 0.f);
    tz[threadIdx.x * 4 + 1] = make_float4(0.f, 0.f, 0.f, 0.f);
    tz[threadIdx.x * 4 + 2] = make_float4(0.f, 0.f, 0.f, 0.f);
    tz[threadIdx.x * 4 + 3] = make_float4(0.f, 0.f, 0.f, 0.f);
    return;
  }
  int idx = blockIdx.x * 256 + threadIdx.x;
  const float* src; ushort4* dst; int i;
  if (idx < 3145728) {
    int which = idx >> 20; i = idx & 1048575;
    src = which == 0 ? q : which == 1 ? k : v;
    dst = qkv_bf + (size_t)which * 1048576 + i;
  } else {
    int w = idx - 3145728; int which = w >> 18; i = w & 262143;
    src = which == 0 ? Wq : which == 1 ? Wk : which == 2 ? Wv : Wp;
    dst = w_bf + w;
  }
  float4 val = ((const float4*)src)[i];
  union { ushort4 u; __hip_bfloat16 h[4]; } c;
  c.h[0] = __float2bfloat16(val.x); c.h[1] = __float2bfloat16(val.y);
  c.h[2] = __float2bfloat16(val.z); c.h[3] = __float2bfloat16(val.w);
  dst[0] = c.u;
}

// ------- bf16 NT GEMM tile: 128x128, K=1024, BK=64 (two 32-col halves) ----
// tailAtomic != nullptr: additionally atomicAdd per-column sums of rows with
// (rowInB + localRow) >= 80 into tailAtomic[col 0..127] (fp32, device scope).
__device__ __forceinline__ void gemm_tile128(
    const __hip_bfloat16* __restrict__ A, const __hip_bfloat16* __restrict__ Bw,
    __hip_bfloat16* __restrict__ C, float* tailAtomic, int rowInB)
{
  const int N = 1024, K = 1024;
  __shared__ __align__(16) __hip_bfloat16 As[2][128 * 32];
  __shared__ __align__(16) __hip_bfloat16 Bs[2][128 * 32];
  const int t = threadIdx.x;
  const int wv = t >> 6, lane = t & 63;
  const int wRow = (wv >> 1) * 64, wCol = (wv & 1) * 64;
  const int mrow = lane & 15, kq = lane >> 4;

  f32x4 acc[4][4] = {};

  for (int k0 = 0; k0 < K; k0 += 64) {
    __syncthreads();
#pragma unroll
    for (int half = 0; half < 2; ++half)
#pragma unroll
      for (int tI = 0; tI < 2; ++tI) {
        int chunk = wv * 2 + tI;              // 0..7, 1024B each within half
        int byteOff = chunk * 1024 + lane * 16;
        int row = byteOff >> 6;
        int colEl = (byteOff & 63) >> 1;
        const __hip_bfloat16* ga = A + (size_t)row * K + k0 + half * 32 + colEl;
        __builtin_amdgcn_global_load_lds(AS1((void*)ga), AS3(&As[half][chunk * 512]), 16, 0, 0);
        const __hip_bfloat16* gb = Bw + (size_t)row * K + k0 + half * 32 + colEl;
        __builtin_amdgcn_global_load_lds(AS1((void*)gb), AS3(&Bs[half][chunk * 512]), 16, 0, 0);
      }
    __syncthreads();

#pragma unroll
    for (int half = 0; half < 2; ++half) {
      bf16x8 af[4], bf[4];
#pragma unroll
      for (int mi = 0; mi < 4; ++mi)
        af[mi] = *(const bf16x8*)&As[half][(wRow + mi * 16 + mrow) * 32 + kq * 8];
#pragma unroll
      for (int ni = 0; ni < 4; ++ni)
        bf[ni] = *(const bf16x8*)&Bs[half][(wCol + ni * 16 + mrow) * 32 + kq * 8];
#pragma unroll
      for (int mi = 0; mi < 4; ++mi)
#pragma unroll
        for (int ni = 0; ni < 4; ++ni)
          acc[mi][ni] = __builtin_amdgcn_mfma_f32_16x16x32_bf16(af[mi], bf[ni], acc[mi][ni], 0, 0, 0);
    }
  }

  // C/D layout: col = lane&15, row = (lane>>4)*4 + r   [m89-verified]
#pragma unroll
  for (int mi = 0; mi < 4; ++mi)
#pragma unroll
    for (int ni = 0; ni < 4; ++ni)
#pragma unroll
      for (int r = 0; r < 4; ++r) {
        int row = wRow + mi * 16 + kq * 4 + r;
        int col = wCol + ni * 16 + mrow;
        C[(size_t)row * N + col] = __float2bfloat16(acc[mi][ni][r]);
      }

  if (tailAtomic) {   // wave-uniform branch (z==2 V blocks only)
#pragma unroll
    for (int ni = 0; ni < 4; ++ni) {
      float s = 0.0f;
#pragma unroll
      for (int mi = 0; mi < 4; ++mi)
#pragma unroll
        for (int r = 0; r < 4; ++r) {
          int localRow = rowInB + wRow + mi * 16 + kq * 4 + r;
          if (localRow >= 80) s += acc[mi][ni][r];
        }
      s += __shfl_xor(s, 16, 64);   // reduce across kq bit0
      s += __shfl_xor(s, 32, 64);   // reduce across kq bit1
      if (kq == 0) atomicAdd(&tailAtomic[wCol + ni * 16 + mrow], s);
    }
  }
}

// QKV: 768 blocks = 8n x (3z x 32m); m-consecutive within XCD for A-strip reuse.
// z==2 (V) blocks also accumulate tails[b][c] = sum_{j>=80} vp[b,j,c] via atomics.
__global__ __launch_bounds__(256) void qkv_gemm_kernel(
    const __hip_bfloat16* __restrict__ QKVbf, const __hip_bfloat16* __restrict__ Wbf,
    __hip_bfloat16* __restrict__ QKVp, float* __restrict__ tails)
{
  int l = blockIdx.x;            // 0..767
  int n = l / 96, mm = l % 96, z = mm >> 5, m = mm & 31;
  float* tailAtomic = nullptr;
  int rowInB = (m & 7) * 128;    // row offset within batch (8 m-tiles per b)
  if (z == 2) tailAtomic = tails + (size_t)(m >> 3) * 1024 + n * 128;
  gemm_tile128(
      QKVbf + (size_t)z * 4194304 + (size_t)m * 131072,
      Wbf + (size_t)z * 1048576 + (size_t)n * 131072,
      QKVp + (size_t)z * 4194304 + (size_t)m * 131072 + n * 128,
      tailAtomic, rowInB);
}

// ------- final GEMM: 64x64 tiles, 1024 blocks (4/CU), BK=64 ---------------
__global__ __launch_bounds__(256) void final_gemm_kernel(
    const __hip_bfloat16* __restrict__ Abf, const __hip_bfloat16* __restrict__ Wpbf,
    float* __restrict__ Out, const float* __restrict__ biasAll)
{
  const int N = 1024, K = 1024;
  int l = blockIdx.x;            // 0..1023
  int m = l & 63, n = l >> 6;    // m fastest -> XCD A-strip reuse
  const __hip_bfloat16* A = Abf + (size_t)m * 65536;      // 64 rows
  const __hip_bfloat16* Bw = Wpbf + (size_t)n * 65536;    // 64 rows
  float* C = Out + (size_t)m * 65536 + n * 64;
  const float* bias = biasAll + n * 64;

  __shared__ __align__(16) __hip_bfloat16 As[2][64 * 32];
  __shared__ __align__(16) __hip_bfloat16 Bs[2][64 * 32];
  const int t = threadIdx.x;
  const int wv = t >> 6, lane = t & 63;
  const int wRow = (wv >> 1) * 32, wCol = (wv & 1) * 32;
  const int mrow = lane & 15, kq = lane >> 4;

  f32x4 acc[2][2] = {};

  for (int k0 = 0; k0 < K; k0 += 64) {
    __syncthreads();
#pragma unroll
    for (int tI = 0; tI < 4; ++tI) {
      int c = wv * 4 + tI;                     // 0..15 chunks of 1024B
      int half, ch;
      const __hip_bfloat16* gsrc;
      __hip_bfloat16* ldst;
      if (c < 8) { half = c >> 2; ch = c & 3;
        int byteOff = ch * 1024 + lane * 16;
        gsrc = A + (size_t)(byteOff >> 6) * K + k0 + half * 32 + ((byteOff & 63) >> 1);
        ldst = &As[half][ch * 512];
      } else { int cb = c - 8; half = cb >> 2; ch = cb & 3;
        int byteOff = ch * 1024 + lane * 16;
        gsrc = Bw + (size_t)(byteOff >> 6) * K + k0 + half * 32 + ((byteOff & 63) >> 1);
        ldst = &Bs[half][ch * 512];
      }
      __builtin_amdgcn_global_load_lds(AS1((void*)gsrc), AS3(ldst), 16, 0, 0);
    }
    __syncthreads();

#pragma unroll
    for (int half = 0; half < 2; ++half) {
      bf16x8 af[2], bf[2];
#pragma unroll
      for (int mi = 0; mi < 2; ++mi)
        af[mi] = *(const bf16x8*)&As[half][(wRow + mi * 16 + mrow) * 32 + kq * 8];
#pragma unroll
      for (int ni = 0; ni < 2; ++ni)
        bf[ni] = *(const bf16x8*)&Bs[half][(wCol + ni * 16 + mrow) * 32 + kq * 8];
#pragma unroll
      for (int mi = 0; mi < 2; ++mi)
#pragma unroll
        for (int ni = 0; ni < 2; ++ni)
          acc[mi][ni] = __builtin_amdgcn_mfma_f32_16x16x32_bf16(af[mi], bf[ni], acc[mi][ni], 0, 0, 0);
    }
  }

#pragma unroll
  for (int mi = 0; mi < 2; ++mi)
#pragma unroll
    for (int ni = 0; ni < 2; ++ni)
#pragma unroll
      for (int r = 0; r < 4; ++r) {
        int row = wRow + mi * 16 + kq * 4 + r;
        int col = wCol + ni * 16 + mrow;
        // out is never re-read on device: bypass L2 with non-temporal store
        __builtin_nontemporal_store(acc[mi][ni][r] + bias[col],
                                    &C[(size_t)row * N + col]);
      }
}

// ---------------- attention: per (b,h, 64-row i-tile) ---------------------
// LDS: bufA holds csl (f32 64x68) during phases A/B, then vpt (bf16 64x104)
// for phase D. wlb + scalars separate. ~30.4 KB total -> 4 blocks/CU.
__global__ __launch_bounds__(256) void attn_kernel(
    const __hip_bfloat16* __restrict__ QP, const __hip_bfloat16* __restrict__ KP,
    const __hip_bfloat16* __restrict__ VP, const float* __restrict__ tails,
    __hip_bfloat16* __restrict__ OUTA)
{
  const int b = blockIdx.z, h = blockIdx.y, i0 = blockIdx.x * 64;
  const int t = threadIdx.x, lane = t & 63, wv = t >> 6;

  __shared__ __align__(16) char bufA[64 * 68 * 4];      // csl f32 / vpt bf16 overlay
  float (*csl)[68] = (float(*)[68])bufA;                // inclusive cumsum
  __hip_bfloat16 (*vpt)[104] = (__hip_bfloat16(*)[104])bufA;  // vp^T B-operand
  __shared__ __align__(16) __hip_bfloat16 wlb[64][96];  // exp(wei-m), A-operand [i][j]
  __shared__ float scl[64], tlw[64], tail[64];

  if (t < 64) tail[t] = tails[(size_t)b * 1024 + h * 64 + t];

  // phase A: p = qp*kp/8, inclusive cumsum over d.
  // 4 threads per row, 16 elements each: vector loads + register cumsum +
  // 3-shuffle prefix across the 4-lane group + float4 stores.
  {
    const int i = t >> 2, seg = t & 3;
    const size_t base = ((size_t)(b * 1024 + i0 + i)) * 1024 + h * 64 + seg * 16;
    bf16x8 q0 = *(const bf16x8*)(QP + base);
    bf16x8 q1 = *(const bf16x8*)(QP + base + 8);
    bf16x8 k0 = *(const bf16x8*)(KP + base);
    bf16x8 k1 = *(const bf16x8*)(KP + base + 8);
    float cs[16];
    float run = 0.0f;
#pragma unroll
    for (int x = 0; x < 8; ++x) {
      run += (float)q0[x] * (float)k0[x] * 0.125f;
      cs[x] = run;
    }
#pragma unroll
    for (int x = 0; x < 8; ++x) {
      run += (float)q1[x] * (float)k1[x] * 0.125f;
      cs[8 + x] = run;
    }
    float t1 = __shfl_up(run, 1, 4);
    float t2 = __shfl_up(run, 2, 4);
    float t3 = __shfl_up(run, 3, 4);
    float off = 0.0f;
    if (seg > 0) off += t1;
    if (seg > 1) off += t2;
    if (seg > 2) off += t3;
    float4* dst = (float4*)&csl[i][seg * 16];
#pragma unroll
    for (int x4 = 0; x4 < 4; ++x4)
      dst[x4] = make_float4(cs[4 * x4] + off, cs[4 * x4 + 1] + off,
                            cs[4 * x4 + 2] + off, cs[4 * x4 + 3] + off);
  }
  __syncthreads();

  // phase B: wei for j<80, softmax max/sum (tail logit = 0, count 944)
  {
    int i = t >> 2, jg = t & 3;
    float wloc[20];
    float mx = 0.0f;  // includes tail's wei=0
#pragma unroll
    for (int q = 0; q < 20; ++q) {
      int j = jg + 4 * q;
      int s = j - 16; s = s < 0 ? 0 : s;
      int e = j + 16; e = e > 64 ? 64 : e;
      float w = csl[i][e - 1] - (s > 0 ? csl[i][s - 1] : 0.0f);
      wloc[q] = w;
      mx = fmaxf(mx, w);
    }
    mx = fmaxf(mx, __shfl_xor(mx, 1, 64));
    mx = fmaxf(mx, __shfl_xor(mx, 2, 64));
    float sum = 0.0f;
#pragma unroll
    for (int q = 0; q < 20; ++q) {
      float e_ = __expf(wloc[q] - mx);
      wlb[i][jg + 4 * q] = __float2bfloat16(e_);
      sum += e_;
    }
#pragma unroll
    for (int q = 0; q < 4; ++q)      // zero pad j = 80..95
      wlb[i][80 + jg + 4 * q] = __float2bfloat16(0.0f);
    sum += __shfl_xor(sum, 1, 64);
    sum += __shfl_xor(sum, 2, 64);
    float tw = __expf(-mx);
    sum += 944.0f * tw;
    if (jg == 0) { scl[i] = 1.0f / sum; tlw[i] = tw / sum; }
  }
  __syncthreads();   // all csl reads done -> safe to overlay with vpt

  // phase C: stage vp^T[d][j] for j<80; zero-pad j=80..95
  for (int idx = t; idx < 80 * 64; idx += 256) {
    int j = idx >> 6, d = idx & 63;
    vpt[d][j] = VP[((size_t)(b * 1024 + j)) * 1024 + h * 64 + d];
  }
  for (int idx = t; idx < 64 * 16; idx += 256) {
    int d = idx >> 4, j = 80 + (idx & 15);
    vpt[d][j] = __float2bfloat16(0.0f);
  }
  __syncthreads();

  // phase D: O[i][d] = sum_j wl[i][j] * vpt[d][j] via MFMA (M=64,N=64,K=96)
  {
    const int mh = (wv >> 1) * 32, nh = (wv & 1) * 32;
    const int mrow = lane & 15, kq = lane >> 4;
    f32x4 acc[2][2] = {};
#pragma unroll
    for (int k0 = 0; k0 < 96; k0 += 32) {
      bf16x8 af[2], bf[2];
#pragma unroll
      for (int mi = 0; mi < 2; ++mi)
        af[mi] = *(const bf16x8*)&wlb[mh + mi * 16 + mrow][k0 + kq * 8];
#pragma unroll
      for (int ni = 0; ni < 2; ++ni)
        bf[ni] = *(const bf16x8*)&vpt[nh + ni * 16 + mrow][k0 + kq * 8];
#pragma unroll
      for (int mi = 0; mi < 2; ++mi)
#pragma unroll
        for (int ni = 0; ni < 2; ++ni)
          acc[mi][ni] = __builtin_amdgcn_mfma_f32_16x16x32_bf16(af[mi], bf[ni], acc[mi][ni], 0, 0, 0);
    }
#pragma unroll
    for (int mi = 0; mi < 2; ++mi)
#pragma unroll
      for (int ni = 0; ni < 2; ++ni)
#pragma unroll
        for (int r = 0; r < 4; ++r) {
          int i = mh + mi * 16 + kq * 4 + r;
          int d = nh + ni * 16 + mrow;
          float o = acc[mi][ni][r] * scl[i] + tlw[i] * tail[d];
          OUTA[((size_t)(b * 1024 + i0 + i)) * 1024 + h * 64 + d] = __float2bfloat16(o);
        }
  }
}

// ---------------- launch ---------------------------------------------------
extern "C" void kernel_launch(void* const* d_in, const int* in_sizes, int n_in,
                              void* d_out, int out_size, void* d_ws, size_t ws_size,
                              hipStream_t stream)
{
  (void)in_sizes; (void)n_in; (void)out_size; (void)ws_size;
  const float* q  = (const float*)d_in[0];
  const float* k  = (const float*)d_in[1];
  const float* v  = (const float*)d_in[2];
  const float* Wq = (const float*)d_in[3];
  const float* Wk = (const float*)d_in[4];
  const float* Wv = (const float*)d_in[5];
  const float* Wp = (const float*)d_in[6];
  const float* bp = (const float*)d_in[7];

  char* ws = (char*)d_ws;
  __hip_bfloat16* qkv_bf = (__hip_bfloat16*)(ws);              // 24 MB (q,k,v bf16)
  __hip_bfloat16* w_bf   = (__hip_bfloat16*)(ws + 25165824);   // 8 MB (Wq,Wk,Wv,Wp)
  __hip_bfloat16* QKVp   = (__hip_bfloat16*)(ws + 33554432);   // 24 MB (qp,kp,vp bf16)
  __hip_bfloat16* OUTA   = (__hip_bfloat16*)(ws + 58720256);   // 8 MB
  float*          tails  = (float*)(ws + 67108864);            // 16 KB fp32
  float* out = (float*)d_out;

  cvt_kernel<<<dim3(16385), 256, 0, stream>>>(q, k, v, Wq, Wk, Wv, Wp,
      (ushort4*)qkv_bf, (ushort4*)w_bf, tails);
  qkv_gemm_kernel<<<dim3(768), 256, 0, stream>>>(qkv_bf, w_bf, QKVp, tails);
  attn_kernel<<<dim3(16, 16, 4), 256, 0, stream>>>(QKVp, QKVp + (size_t)4194304,
                                                   QKVp + (size_t)2 * 4194304, tails, OUTA);
  final_gemm_kernel<<<dim3(1024), 256, 0, stream>>>(OUTA, w_bf + (size_t)3 * 1048576,
                                                    out, bp);
}